// Round 1
// baseline (521.526 us; speedup 1.0000x reference)
//
#include <hip/hip_runtime.h>

#define NN 50000
#define NE 800000

// ---------------- CSR build ----------------

__global__ __launch_bounds__(256) void k_count(const int* __restrict__ dst,
                                               int* __restrict__ cnt, int E) {
    int e = blockIdx.x * 256 + threadIdx.x;
    if (e < E) atomicAdd(&cnt[dst[e]], 1);
}

__global__ __launch_bounds__(256) void k_scan1(const int* __restrict__ cnt,
                                               int* __restrict__ rowstart,
                                               int* __restrict__ sums, int n) {
    __shared__ int s[256];
    int t = threadIdx.x, gid = blockIdx.x * 256 + t;
    int v = (gid < n) ? cnt[gid] : 0;
    s[t] = v; __syncthreads();
    for (int off = 1; off < 256; off <<= 1) {
        int x = (t >= off) ? s[t - off] : 0;
        __syncthreads();
        s[t] += x; __syncthreads();
    }
    if (gid < n) rowstart[gid] = s[t] - v;   // exclusive (partial, per-block)
    if (t == 255) sums[blockIdx.x] = s[t];
}

__global__ __launch_bounds__(256) void k_scan2(const int* __restrict__ sums,
                                               int* __restrict__ offs, int nb) {
    __shared__ int s[256];
    int t = threadIdx.x;
    int v = (t < nb) ? sums[t] : 0;
    s[t] = v; __syncthreads();
    for (int off = 1; off < 256; off <<= 1) {
        int x = (t >= off) ? s[t - off] : 0;
        __syncthreads();
        s[t] += x; __syncthreads();
    }
    offs[t] = s[t] - v;                      // exclusive scan of block sums
}

__global__ __launch_bounds__(256) void k_scan3(const int* __restrict__ cnt,
                                               int* __restrict__ rowstart,
                                               const int* __restrict__ offs,
                                               float* __restrict__ dinv, int n) {
    int gid = blockIdx.x * 256 + threadIdx.x;
    if (gid < n) {
        rowstart[gid] += offs[blockIdx.x];
        // deg includes the self loop: cnt + 1 (so max(deg,1) is automatic)
        dinv[gid] = rsqrtf((float)cnt[gid] + 1.0f);
    }
}

__global__ __launch_bounds__(256) void k_scatter(const int* __restrict__ src,
                                                 const int* __restrict__ dst,
                                                 const int* __restrict__ rowstart,
                                                 int* __restrict__ cursor,
                                                 const float* __restrict__ dinv,
                                                 int2* __restrict__ csr, int E) {
    int e = blockIdx.x * 256 + threadIdx.x;
    if (e < E) {
        int s = src[e], d = dst[e];
        int p = rowstart[d] + atomicAdd(&cursor[d], 1);
        float w = dinv[s] * dinv[d];
        csr[p] = make_int2(s, __float_as_int(w));
    }
}

// ---------------- dense GEMM: T[n,F] = A[n,K] @ W[K,F] ----------------
// block = 256 threads = 4 waves; block covers 64 nodes.
// lane: fg = lane%16 -> 4 consecutive feats; ng = lane/16 -> 4-node group.
// per lane: 4 nodes x 4 feats register tile; W staged in LDS (stride 64).

template <int K, int F>
__global__ __launch_bounds__(256) void k_gemm(const float* __restrict__ A,
                                              const float* __restrict__ W,
                                              float* __restrict__ T, int n) {
    __shared__ float wlds[K * 64];
    int tid = threadIdx.x;
    for (int i = tid; i < K * 64; i += 256) {
        int k = i >> 6, f = i & 63;
        wlds[i] = (f < F) ? W[k * F + f] : 0.0f;
    }
    __syncthreads();

    int lane = tid & 63, wid = tid >> 6;
    int fg = lane & 15, ng = lane >> 4;
    int nodebase = blockIdx.x * 64 + wid * 16 + ng * 4;

    float4 acc[4] = {};
    for (int k = 0; k < K; k += 4) {
        float4 a[4];
        #pragma unroll
        for (int r = 0; r < 4; ++r) {
            int node = nodebase + r;
            a[r] = (node < n) ? *(const float4*)&A[node * K + k]
                              : float4{0.f, 0.f, 0.f, 0.f};
        }
        #pragma unroll
        for (int kk = 0; kk < 4; ++kk) {
            float4 wv = *(const float4*)&wlds[(k + kk) * 64 + fg * 4];
            #pragma unroll
            for (int r = 0; r < 4; ++r) {
                float av = (kk == 0) ? a[r].x : (kk == 1) ? a[r].y
                         : (kk == 2) ? a[r].z : a[r].w;
                acc[r].x += av * wv.x;
                acc[r].y += av * wv.y;
                acc[r].z += av * wv.z;
                acc[r].w += av * wv.w;
            }
        }
    }

    if (fg * 4 + 3 < F) {
        #pragma unroll
        for (int r = 0; r < 4; ++r) {
            int node = nodebase + r;
            if (node < n) *(float4*)&T[node * F + fg * 4] = acc[r];
        }
    }
}

// ---------------- normalized aggregation (gather over CSR) ----------------
// one wave per dst node, lane = feature. self-loop = dinv^2 * t[node].

__global__ __launch_bounds__(256) void k_gather(const float* __restrict__ T,
                                                const int2* __restrict__ csr,
                                                const int* __restrict__ rowstart,
                                                const int* __restrict__ cnt,
                                                const float* __restrict__ dinv,
                                                const float* __restrict__ bias,
                                                float* __restrict__ OUT,
                                                int n, int F, int relu) {
    int wid = threadIdx.x >> 6, lane = threadIdx.x & 63;
    int node = blockIdx.x * 4 + wid;
    if (node >= n || lane >= F) return;   // no cross-lane ops below: safe

    float di = dinv[node];
    float acc = T[node * F + lane] * di * di;   // self loop
    int s0 = rowstart[node], c = cnt[node];
    for (int j = 0; j < c; ++j) {
        int2 cw = csr[s0 + j];
        acc += __int_as_float(cw.y) * T[cw.x * F + lane];
    }
    float r = acc + bias[lane];
    if (relu) r = fmaxf(r, 0.0f);
    OUT[node * F + lane] = r;
}

// ---------------- launch ----------------

extern "C" void kernel_launch(void* const* d_in, const int* in_sizes, int n_in,
                              void* d_out, int out_size, void* d_ws, size_t ws_size,
                              hipStream_t stream) {
    const float* x  = (const float*)d_in[0];
    const int*   ei = (const int*)d_in[1];
    const float* W1 = (const float*)d_in[2];
    const float* b1 = (const float*)d_in[3];
    const float* W2 = (const float*)d_in[4];
    const float* b2 = (const float*)d_in[5];
    const float* W3 = (const float*)d_in[6];
    const float* b3 = (const float*)d_in[7];
    float* out = (float*)d_out;

    const int N = NN, E = NE;
    const int* src = ei;
    const int* dst = ei + E;

    // workspace layout (ws re-poisoned to 0xAA before every call)
    int*   cnt      = (int*)d_ws;                 // N
    int*   cursor   = cnt + N;                    // N  (adjacent to cnt: one memset)
    int*   rowstart = cursor + N;                 // N
    float* dinv     = (float*)(rowstart + N);     // N
    int*   sums     = (int*)(dinv + N);           // 256
    int*   offs     = sums + 256;                 // 256
    int2*  csr      = (int2*)(offs + 256);        // E pairs (col, norm-bits)
    float* tbuf     = (float*)(csr + E);          // N*64
    float* hbuf     = tbuf + (size_t)N * 64;      // N*64
    // total ~33 MB

    hipMemsetAsync(cnt, 0, sizeof(int) * 2 * N, stream);   // cnt + cursor

    int eb = (E + 255) / 256;       // 3125
    int nb = (N + 255) / 256;       // 196
    k_count  <<<eb, 256, 0, stream>>>(dst, cnt, E);
    k_scan1  <<<nb, 256, 0, stream>>>(cnt, rowstart, sums, N);
    k_scan2  <<<1,  256, 0, stream>>>(sums, offs, nb);
    k_scan3  <<<nb, 256, 0, stream>>>(cnt, rowstart, offs, dinv, N);
    k_scatter<<<eb, 256, 0, stream>>>(src, dst, rowstart, cursor, dinv, csr, E);

    int gb = (N + 63) / 64;         // 782
    int ab = (N + 3) / 4;           // 12500

    k_gemm<128, 64><<<gb, 256, 0, stream>>>(x, W1, tbuf, N);
    k_gather<<<ab, 256, 0, stream>>>(tbuf, csr, rowstart, cnt, dinv, b1, hbuf, N, 64, 1);
    k_gemm<64, 64><<<gb, 256, 0, stream>>>(hbuf, W2, tbuf, N);
    k_gather<<<ab, 256, 0, stream>>>(tbuf, csr, rowstart, cnt, dinv, b2, hbuf, N, 64, 1);
    k_gemm<64, 40><<<gb, 256, 0, stream>>>(hbuf, W3, tbuf, N);
    k_gather<<<ab, 256, 0, stream>>>(tbuf, csr, rowstart, cnt, dinv, b3, out, N, 40, 0);
}

// Round 2
// 437.614 us; speedup vs baseline: 1.1917x; 1.1917x over previous
//
#include <hip/hip_runtime.h>

#define NN 50000
#define NE 800000

// ---------------- CSR build ----------------

__global__ __launch_bounds__(256) void k_count(const int* __restrict__ dst,
                                               int* __restrict__ cnt, int E) {
    int e = blockIdx.x * 256 + threadIdx.x;
    if (e < E) atomicAdd(&cnt[dst[e]], 1);
}

__global__ __launch_bounds__(256) void k_scan1(const int* __restrict__ cnt,
                                               int* __restrict__ rowstart,
                                               int* __restrict__ sums, int n) {
    __shared__ int s[256];
    int t = threadIdx.x, gid = blockIdx.x * 256 + t;
    int v = (gid < n) ? cnt[gid] : 0;
    s[t] = v; __syncthreads();
    for (int off = 1; off < 256; off <<= 1) {
        int x = (t >= off) ? s[t - off] : 0;
        __syncthreads();
        s[t] += x; __syncthreads();
    }
    if (gid < n) rowstart[gid] = s[t] - v;   // exclusive (partial, per-block)
    if (t == 255) sums[blockIdx.x] = s[t];
}

__global__ __launch_bounds__(256) void k_scan2(const int* __restrict__ sums,
                                               int* __restrict__ offs, int nb) {
    __shared__ int s[256];
    int t = threadIdx.x;
    int v = (t < nb) ? sums[t] : 0;
    s[t] = v; __syncthreads();
    for (int off = 1; off < 256; off <<= 1) {
        int x = (t >= off) ? s[t - off] : 0;
        __syncthreads();
        s[t] += x; __syncthreads();
    }
    offs[t] = s[t] - v;                      // exclusive scan of block sums
}

__global__ __launch_bounds__(256) void k_scan3(const int* __restrict__ cnt,
                                               int* __restrict__ rowstart,
                                               const int* __restrict__ offs,
                                               float* __restrict__ dinv, int n) {
    int gid = blockIdx.x * 256 + threadIdx.x;
    if (gid < n) {
        rowstart[gid] += offs[blockIdx.x];
        // deg includes the self loop: cnt + 1 (so max(deg,1) is automatic)
        dinv[gid] = rsqrtf((float)cnt[gid] + 1.0f);
    }
}

__global__ __launch_bounds__(256) void k_scatter(const int* __restrict__ src,
                                                 const int* __restrict__ dst,
                                                 const int* __restrict__ rowstart,
                                                 int* __restrict__ cursor,
                                                 const float* __restrict__ dinv,
                                                 int2* __restrict__ csr, int E) {
    int e = blockIdx.x * 256 + threadIdx.x;
    if (e < E) {
        int s = src[e], d = dst[e];
        int p = rowstart[d] + atomicAdd(&cursor[d], 1);
        float w = dinv[s] * dinv[d];
        csr[p] = make_int2(s, __float_as_int(w));
    }
}

// ---------------- dense GEMM: T[n,F] = A[n,K] @ W[K,F] ----------------
// block = 256 threads = 4 waves; block covers 64 nodes.
// lane: fg = lane%16 -> 4 consecutive feats; ng = lane/16 -> 4-node group.
// per lane: 4 nodes x 4 feats register tile; W staged in LDS (stride 64).

template <int K, int F>
__global__ __launch_bounds__(256) void k_gemm(const float* __restrict__ A,
                                              const float* __restrict__ W,
                                              float* __restrict__ T, int n) {
    __shared__ float wlds[K * 64];
    int tid = threadIdx.x;
    for (int i = tid; i < K * 64; i += 256) {
        int k = i >> 6, f = i & 63;
        wlds[i] = (f < F) ? W[k * F + f] : 0.0f;
    }
    __syncthreads();

    int lane = tid & 63, wid = tid >> 6;
    int fg = lane & 15, ng = lane >> 4;
    int nodebase = blockIdx.x * 64 + wid * 16 + ng * 4;

    float4 acc[4] = {};
    for (int k = 0; k < K; k += 4) {
        float4 a[4];
        #pragma unroll
        for (int r = 0; r < 4; ++r) {
            int node = nodebase + r;
            a[r] = (node < n) ? *(const float4*)&A[node * K + k]
                              : float4{0.f, 0.f, 0.f, 0.f};
        }
        #pragma unroll
        for (int kk = 0; kk < 4; ++kk) {
            float4 wv = *(const float4*)&wlds[(k + kk) * 64 + fg * 4];
            #pragma unroll
            for (int r = 0; r < 4; ++r) {
                float av = (kk == 0) ? a[r].x : (kk == 1) ? a[r].y
                         : (kk == 2) ? a[r].z : a[r].w;
                acc[r].x += av * wv.x;
                acc[r].y += av * wv.y;
                acc[r].z += av * wv.z;
                acc[r].w += av * wv.w;
            }
        }
    }

    if (fg * 4 + 3 < F) {
        #pragma unroll
        for (int r = 0; r < 4; ++r) {
            int node = nodebase + r;
            if (node < n) *(float4*)&T[node * F + fg * 4] = acc[r];
        }
    }
}

// ---------------- normalized aggregation (gather over CSR) ----------------
// one wave per dst node, lane = feature. self-loop = dinv^2 * t[node].
// Edge loop batched 8-wide: 8 independent csr loads -> 8 independent row
// gathers in flight, tail predicated inside the batch (w=0, idx=0) so no
// serial remainder chain survives. This is the latency fix for R1's 82us.

#define GB 8

__global__ __launch_bounds__(256) void k_gather(const float* __restrict__ T,
                                                const int2* __restrict__ csr,
                                                const int* __restrict__ rowstart,
                                                const int* __restrict__ cnt,
                                                const float* __restrict__ dinv,
                                                const float* __restrict__ bias,
                                                float* __restrict__ OUT,
                                                int n, int F, int relu) {
    int wid = threadIdx.x >> 6, lane = threadIdx.x & 63;
    int node = blockIdx.x * 4 + wid;
    if (node >= n || lane >= F) return;   // no cross-lane ops below: safe

    float di = dinv[node];
    float acc = T[node * F + lane] * di * di;   // self loop
    int s0 = rowstart[node], c = cnt[node];

    for (int j = 0; j < c; j += GB) {
        int   col[GB];
        float w[GB];
        #pragma unroll
        for (int u = 0; u < GB; ++u) {
            int idx = j + u;
            int2 cw = (idx < c) ? csr[s0 + idx] : make_int2(0, 0);
            col[u] = cw.x;
            w[u]   = __int_as_float(cw.y);   // 0 bits == 0.0f for tail
        }
        float tv[GB];
        #pragma unroll
        for (int u = 0; u < GB; ++u) tv[u] = T[col[u] * F + lane];
        #pragma unroll
        for (int u = 0; u < GB; ++u) acc += w[u] * tv[u];
    }

    float r = acc + bias[lane];
    if (relu) r = fmaxf(r, 0.0f);
    OUT[node * F + lane] = r;
}

// ---------------- launch ----------------

extern "C" void kernel_launch(void* const* d_in, const int* in_sizes, int n_in,
                              void* d_out, int out_size, void* d_ws, size_t ws_size,
                              hipStream_t stream) {
    const float* x  = (const float*)d_in[0];
    const int*   ei = (const int*)d_in[1];
    const float* W1 = (const float*)d_in[2];
    const float* b1 = (const float*)d_in[3];
    const float* W2 = (const float*)d_in[4];
    const float* b2 = (const float*)d_in[5];
    const float* W3 = (const float*)d_in[6];
    const float* b3 = (const float*)d_in[7];
    float* out = (float*)d_out;

    const int N = NN, E = NE;
    const int* src = ei;
    const int* dst = ei + E;

    // workspace layout (ws re-poisoned to 0xAA before every call)
    int*   cnt      = (int*)d_ws;                 // N
    int*   cursor   = cnt + N;                    // N  (adjacent to cnt: one memset)
    int*   rowstart = cursor + N;                 // N
    float* dinv     = (float*)(rowstart + N);     // N
    int*   sums     = (int*)(dinv + N);           // 256
    int*   offs     = sums + 256;                 // 256
    int2*  csr      = (int2*)(offs + 256);        // E pairs (col, norm-bits)
    float* tbuf     = (float*)(csr + E);          // N*64
    float* hbuf     = tbuf + (size_t)N * 64;      // N*64
    // total ~33 MB

    hipMemsetAsync(cnt, 0, sizeof(int) * 2 * N, stream);   // cnt + cursor

    int eb = (E + 255) / 256;       // 3125
    int nb = (N + 255) / 256;       // 196
    k_count  <<<eb, 256, 0, stream>>>(dst, cnt, E);
    k_scan1  <<<nb, 256, 0, stream>>>(cnt, rowstart, sums, N);
    k_scan2  <<<1,  256, 0, stream>>>(sums, offs, nb);
    k_scan3  <<<nb, 256, 0, stream>>>(cnt, rowstart, offs, dinv, N);
    k_scatter<<<eb, 256, 0, stream>>>(src, dst, rowstart, cursor, dinv, csr, E);

    int gb = (N + 63) / 64;         // 782
    int ab = (N + 3) / 4;           // 12500

    k_gemm<128, 64><<<gb, 256, 0, stream>>>(x, W1, tbuf, N);
    k_gather<<<ab, 256, 0, stream>>>(tbuf, csr, rowstart, cnt, dinv, b1, hbuf, N, 64, 1);
    k_gemm<64, 64><<<gb, 256, 0, stream>>>(hbuf, W2, tbuf, N);
    k_gather<<<ab, 256, 0, stream>>>(tbuf, csr, rowstart, cnt, dinv, b2, hbuf, N, 64, 1);
    k_gemm<64, 40><<<gb, 256, 0, stream>>>(hbuf, W3, tbuf, N);
    k_gather<<<ab, 256, 0, stream>>>(tbuf, csr, rowstart, cnt, dinv, b3, out, N, 40, 0);
}

// Round 3
// 388.896 us; speedup vs baseline: 1.3410x; 1.1253x over previous
//
#include <hip/hip_runtime.h>

#define NN 50000
#define NE 800000

// ---------------- CSR build ----------------

__global__ __launch_bounds__(256) void k_count(const int* __restrict__ dst,
                                               int* __restrict__ cnt, int E) {
    int e = blockIdx.x * 256 + threadIdx.x;
    if (e < E) atomicAdd(&cnt[dst[e]], 1);
}

__global__ __launch_bounds__(256) void k_scan1(const int* __restrict__ cnt,
                                               int* __restrict__ rowstart,
                                               int* __restrict__ sums, int n) {
    __shared__ int s[256];
    int t = threadIdx.x, gid = blockIdx.x * 256 + t;
    int v = (gid < n) ? cnt[gid] : 0;
    s[t] = v; __syncthreads();
    for (int off = 1; off < 256; off <<= 1) {
        int x = (t >= off) ? s[t - off] : 0;
        __syncthreads();
        s[t] += x; __syncthreads();
    }
    if (gid < n) rowstart[gid] = s[t] - v;   // exclusive (partial, per-block)
    if (t == 255) sums[blockIdx.x] = s[t];
}

__global__ __launch_bounds__(256) void k_scan2(const int* __restrict__ sums,
                                               int* __restrict__ offs, int nb) {
    __shared__ int s[256];
    int t = threadIdx.x;
    int v = (t < nb) ? sums[t] : 0;
    s[t] = v; __syncthreads();
    for (int off = 1; off < 256; off <<= 1) {
        int x = (t >= off) ? s[t - off] : 0;
        __syncthreads();
        s[t] += x; __syncthreads();
    }
    offs[t] = s[t] - v;                      // exclusive scan of block sums
}

__global__ __launch_bounds__(256) void k_scan3(const int* __restrict__ cnt,
                                               int* __restrict__ rowstart,
                                               const int* __restrict__ offs,
                                               float* __restrict__ dinv, int n) {
    int gid = blockIdx.x * 256 + threadIdx.x;
    if (gid < n) {
        rowstart[gid] += offs[blockIdx.x];
        // deg includes the self loop: cnt + 1 (so max(deg,1) is automatic)
        dinv[gid] = rsqrtf((float)cnt[gid] + 1.0f);
    }
}

__global__ __launch_bounds__(256) void k_scatter(const int* __restrict__ src,
                                                 const int* __restrict__ dst,
                                                 const int* __restrict__ rowstart,
                                                 int* __restrict__ cursor,
                                                 const float* __restrict__ dinv,
                                                 int2* __restrict__ csr, int E) {
    int e = blockIdx.x * 256 + threadIdx.x;
    if (e < E) {
        int s = src[e], d = dst[e];
        int p = rowstart[d] + atomicAdd(&cursor[d], 1);
        float w = dinv[s] * dinv[d];
        csr[p] = make_int2(s, __float_as_int(w));
    }
}

// ---------------- dense GEMM: T[n,F] = A[n,K] @ W[K,F] ----------------
// block = 256 threads = 4 waves; block covers 64 nodes.
// lane: fg = lane%16 -> 4 consecutive feats; ng = lane/16 -> 4-node group.
// per lane: 4 nodes x 4 feats register tile; W staged in LDS (stride 64).
// R2 fix: WITHOUT the unroll cap the compiler fully unrolls K/4=32 iters,
// hoists 32x4 float4 loads -> 256 VGPRs + scratch spill + 1.2% occupancy
// (one 40ms first-touch dispatch). unroll 2 keeps <=8 float4 A-loads live.

template <int K, int F>
__global__ __launch_bounds__(256) void k_gemm(const float* __restrict__ A,
                                              const float* __restrict__ W,
                                              float* __restrict__ T, int n) {
    __shared__ float wlds[K * 64];
    int tid = threadIdx.x;
    for (int i = tid; i < K * 64; i += 256) {
        int k = i >> 6, f = i & 63;
        wlds[i] = (f < F) ? W[k * F + f] : 0.0f;
    }
    __syncthreads();

    int lane = tid & 63, wid = tid >> 6;
    int fg = lane & 15, ng = lane >> 4;
    int nodebase = blockIdx.x * 64 + wid * 16 + ng * 4;

    float4 acc[4] = {};
    #pragma unroll 2
    for (int k = 0; k < K; k += 4) {
        float4 a[4];
        #pragma unroll
        for (int r = 0; r < 4; ++r) {
            int node = nodebase + r;
            a[r] = (node < n) ? *(const float4*)&A[node * K + k]
                              : float4{0.f, 0.f, 0.f, 0.f};
        }
        #pragma unroll
        for (int kk = 0; kk < 4; ++kk) {
            float4 wv = *(const float4*)&wlds[(k + kk) * 64 + fg * 4];
            #pragma unroll
            for (int r = 0; r < 4; ++r) {
                float av = (kk == 0) ? a[r].x : (kk == 1) ? a[r].y
                         : (kk == 2) ? a[r].z : a[r].w;
                acc[r].x += av * wv.x;
                acc[r].y += av * wv.y;
                acc[r].z += av * wv.z;
                acc[r].w += av * wv.w;
            }
        }
    }

    if (fg * 4 + 3 < F) {
        #pragma unroll
        for (int r = 0; r < 4; ++r) {
            int node = nodebase + r;
            if (node < n) *(float4*)&T[node * F + fg * 4] = acc[r];
        }
    }
}

// ---------------- normalized aggregation (gather over CSR) ----------------
// one wave per dst node, lane = feature. self-loop = dinv^2 * t[node].
// Edge loop batched GB-wide: GB independent csr loads -> GB independent row
// gathers in flight, tail predicated inside the batch (w=0, idx=0) so no
// serial remainder chain survives. GB=16 covers avg degree in one batch.

#define GB 16

__global__ __launch_bounds__(256) void k_gather(const float* __restrict__ T,
                                                const int2* __restrict__ csr,
                                                const int* __restrict__ rowstart,
                                                const int* __restrict__ cnt,
                                                const float* __restrict__ dinv,
                                                const float* __restrict__ bias,
                                                float* __restrict__ OUT,
                                                int n, int F, int relu) {
    int wid = threadIdx.x >> 6, lane = threadIdx.x & 63;
    int node = blockIdx.x * 4 + wid;
    if (node >= n || lane >= F) return;   // no cross-lane ops below: safe

    float di = dinv[node];
    float acc = T[node * F + lane] * di * di;   // self loop
    int s0 = rowstart[node], c = cnt[node];

    for (int j = 0; j < c; j += GB) {
        int   col[GB];
        float w[GB];
        #pragma unroll
        for (int u = 0; u < GB; ++u) {
            int idx = j + u;
            int2 cw = (idx < c) ? csr[s0 + idx] : make_int2(0, 0);
            col[u] = cw.x;
            w[u]   = __int_as_float(cw.y);   // 0 bits == 0.0f for tail
        }
        float tv[GB];
        #pragma unroll
        for (int u = 0; u < GB; ++u) tv[u] = T[col[u] * F + lane];
        #pragma unroll
        for (int u = 0; u < GB; ++u) acc += w[u] * tv[u];
    }

    float r = acc + bias[lane];
    if (relu) r = fmaxf(r, 0.0f);
    OUT[node * F + lane] = r;
}

// ---------------- launch ----------------

extern "C" void kernel_launch(void* const* d_in, const int* in_sizes, int n_in,
                              void* d_out, int out_size, void* d_ws, size_t ws_size,
                              hipStream_t stream) {
    const float* x  = (const float*)d_in[0];
    const int*   ei = (const int*)d_in[1];
    const float* W1 = (const float*)d_in[2];
    const float* b1 = (const float*)d_in[3];
    const float* W2 = (const float*)d_in[4];
    const float* b2 = (const float*)d_in[5];
    const float* W3 = (const float*)d_in[6];
    const float* b3 = (const float*)d_in[7];
    float* out = (float*)d_out;

    const int N = NN, E = NE;
    const int* src = ei;
    const int* dst = ei + E;

    // workspace layout (ws re-poisoned to 0xAA before every call)
    int*   cnt      = (int*)d_ws;                 // N
    int*   cursor   = cnt + N;                    // N  (adjacent to cnt: one memset)
    int*   rowstart = cursor + N;                 // N
    float* dinv     = (float*)(rowstart + N);     // N
    int*   sums     = (int*)(dinv + N);           // 256
    int*   offs     = sums + 256;                 // 256
    int2*  csr      = (int2*)(offs + 256);        // E pairs (col, norm-bits)
    float* tbuf     = (float*)(csr + E);          // N*64
    float* hbuf     = tbuf + (size_t)N * 64;      // N*64
    // total ~33 MB

    hipMemsetAsync(cnt, 0, sizeof(int) * 2 * N, stream);   // cnt + cursor

    int eb = (E + 255) / 256;       // 3125
    int nb = (N + 255) / 256;       // 196
    k_count  <<<eb, 256, 0, stream>>>(dst, cnt, E);
    k_scan1  <<<nb, 256, 0, stream>>>(cnt, rowstart, sums, N);
    k_scan2  <<<1,  256, 0, stream>>>(sums, offs, nb);
    k_scan3  <<<nb, 256, 0, stream>>>(cnt, rowstart, offs, dinv, N);
    k_scatter<<<eb, 256, 0, stream>>>(src, dst, rowstart, cursor, dinv, csr, E);

    int gb = (N + 63) / 64;         // 782
    int ab = (N + 3) / 4;           // 12500

    k_gemm<128, 64><<<gb, 256, 0, stream>>>(x, W1, tbuf, N);
    k_gather<<<ab, 256, 0, stream>>>(tbuf, csr, rowstart, cnt, dinv, b1, hbuf, N, 64, 1);
    k_gemm<64, 64><<<gb, 256, 0, stream>>>(hbuf, W2, tbuf, N);
    k_gather<<<ab, 256, 0, stream>>>(tbuf, csr, rowstart, cnt, dinv, b2, hbuf, N, 64, 1);
    k_gemm<64, 40><<<gb, 256, 0, stream>>>(hbuf, W3, tbuf, N);
    k_gather<<<ab, 256, 0, stream>>>(tbuf, csr, rowstart, cnt, dinv, b3, out, N, 40, 0);
}